// Round 1
// baseline (1209.346 us; speedup 1.0000x reference)
//
#include <hip/hip_runtime.h>
#include <math.h>

#define B_    64
#define L_    512
#define C_    321
#define PRED_ 96
#define N_    64
#define HID_  32
#define BC_   (B_*C_)   // 20544
#define SROW_ 528       // padded stride for seasonal rows (520 used)
#define EPS_  1e-5f
#define ALPHA_ 0.2f
#define GR_   16        // rows per block in bn-stat kernels
#define RB_   8         // rows per block in final kernel
#define NBLK2_ (BC_/GR_) // 1284

__device__ __forceinline__ float gelu_f(float x){
  return 0.5f*x*(1.0f + erff(x*0.70710678118654752440f));
}

// ---------- K0: fold seas/tr matmuls through fus ----------
__global__ __launch_bounds__(256) void k0_fold(
    const float* __restrict__ seas_w, const float* __restrict__ tr_w,
    const float* __restrict__ fus_w,
    float* __restrict__ W_sfT, float* __restrict__ W_tfT) {
  int idx = blockIdx.x*256 + threadIdx.x;
  if (idx >= 1536*96) return;
  int k = idx/96, j = idx - k*96;
  if (k < 1024) {
    float acc = 0.f;
    for (int i=0;i<96;++i) acc = fmaf(fus_w[j*192+i], seas_w[i*1024+k], acc);
    W_sfT[k*96+j] = acc;
  } else {
    int l = k-1024;
    float acc = 0.f;
    for (int i=0;i<96;++i) acc = fmaf(fus_w[j*192+96+i], tr_w[i*512+l], acc);
    W_tfT[l*96+j] = acc;
  }
}

__global__ void k0b_bias(
    const float* __restrict__ seas_b, const float* __restrict__ tr_b,
    const float* __restrict__ fus_w, const float* __restrict__ fus_b,
    float* __restrict__ biasc) {
  int j = threadIdx.x;
  if (j >= 96) return;
  float acc = fus_b[j];
  for (int i=0;i<96;++i) {
    acc = fmaf(fus_w[j*192+i], seas_b[i], acc);
    acc = fmaf(fus_w[j*192+96+i], tr_b[i], acc);
  }
  biasc[j] = acc;
}

// ---------- K1: RevIN stats + EMA scan; store raw seasonal/trend ----------
// thread = one (b,c) row; LDS transpose for coalesced row-major writes
__global__ __launch_bounds__(64) void k1_revin_ema(
    const float* __restrict__ x, const float* __restrict__ rev_w, const float* __restrict__ rev_b,
    float* __restrict__ s_raw, float* __restrict__ t_raw, float* __restrict__ rowpar) {
  __shared__ float st[64][65];
  __shared__ float tt[64][65];
  int lane = threadIdx.x;
  int r = blockIdx.x*64 + lane;
  int b = r / C_, c = r - b*C_;
  const float* xp = x + ((size_t)b*L_)*C_ + c;
  int r0 = blockIdx.x*64;
  float sum=0.f, sq=0.f, tcur=0.f, slast=0.f;
  for (int tile=0; tile<8; ++tile) {
    for (int i=0;i<64;++i) {
      int l = tile*64+i;
      float v = xp[(size_t)l*C_];
      sum += v; sq = fmaf(v,v,sq);
      tcur = (l==0) ? v : fmaf(ALPHA_, v, 0.8f*tcur);
      st[i][lane] = v - tcur;
      tt[i][lane] = tcur;
      if (l == 511) slast = v - tcur;
    }
    __syncthreads();
    for (int i=0;i<64;++i) {
      s_raw[(size_t)(r0+i)*SROW_ + tile*64 + lane] = st[lane][i];
      t_raw[(size_t)(r0+i)*L_   + tile*64 + lane] = tt[lane][i];
    }
    __syncthreads();
  }
  // padding: cols 512..519 = value at l=511
  for (int k=0;k<8;++k) s_raw[(size_t)r*SROW_ + 512 + k] = slast;
  float mean = sum * (1.0f/512.0f);
  float var  = (sq - sum*sum*(1.0f/512.0f)) * (1.0f/511.0f);
  var = fmaxf(var, 0.f);
  float stdv = sqrtf(var) + EPS_;
  float rwc = rev_w[c], rbc = rev_b[c];
  float a = rwc / stdv;             // seasonal/trend scale
  float g = rbc - mean*a;           // trend shift
  float inva = stdv / rwc;          // inverse-RevIN scale
  ((float4*)rowpar)[r] = make_float4(a, g, mean, inva);
}

// ---------- K2: BN1 statistics of gelu(fc1(sp)) ----------
__global__ __launch_bounds__(256) void k2_bn1stats(
    const float* __restrict__ s_raw, const float* __restrict__ rowpar,
    const float* __restrict__ fc1_w, const float* __restrict__ fc1_b,
    float* __restrict__ partials) {
  __shared__ float sl[GR_*SROW_];
  __shared__ float w1[512];
  __shared__ float b1[32];
  __shared__ float al[GR_];
  __shared__ float red[2][GR_*64];
  int t = threadIdx.x;
  int row0 = blockIdx.x*GR_;
  if (t < GR_) al[t] = rowpar[(size_t)(row0+t)*4];
  for (int idx=t; idx<512; idx+=256) w1[idx] = fc1_w[idx];
  if (t < 32) b1[t] = fc1_b[t];
  __syncthreads();
  for (int idx=t; idx<GR_*520; idx+=256) {
    int rr = idx/520, cc = idx - rr*520;
    sl[rr*SROW_+cc] = s_raw[(size_t)(row0+rr)*SROW_+cc] * al[rr];
  }
  __syncthreads();
  int lr = t >> 4, ng = t & 15;
  for (int q=0;q<4;++q) {
    int n = ng + 16*q;
    float sp[16];
    #pragma unroll
    for (int p=0;p<16;++p) sp[p] = sl[lr*SROW_ + n*8 + p];
    float s1=0.f, s2=0.f;
    #pragma unroll
    for (int hid=0; hid<32; ++hid) {
      float acc = b1[hid];
      #pragma unroll
      for (int p=0;p<16;++p) acc = fmaf(sp[p], w1[hid*16+p], acc);
      float gv = gelu_f(acc);
      s1 += gv; s2 = fmaf(gv,gv,s2);
    }
    red[0][lr*64+n] = s1;
    red[1][lr*64+n] = s2;
  }
  __syncthreads();
  if (t < 64) {
    float S1=0.f, S2=0.f;
    for (int lr2=0; lr2<GR_; ++lr2) { S1 += red[0][lr2*64+t]; S2 += red[1][lr2*64+t]; }
    partials[((size_t)blockIdx.x*64+t)*2+0] = S1;
    partials[((size_t)blockIdx.x*64+t)*2+1] = S2;
  }
}

// ---------- bn reduce: partials -> scale/shift ----------
__global__ __launch_bounds__(256) void k_bnreduce(
    const float* __restrict__ partials, int nblk,
    const float* __restrict__ bnw, const float* __restrict__ bnb,
    float* __restrict__ scale, float* __restrict__ shift) {
  __shared__ float red[2][256];
  int n = blockIdx.x, t = threadIdx.x;
  float s1=0.f, s2=0.f;
  for (int i=t; i<nblk; i+=256) {
    s1 += partials[((size_t)i*64+n)*2+0];
    s2 += partials[((size_t)i*64+n)*2+1];
  }
  red[0][t]=s1; red[1][t]=s2;
  __syncthreads();
  for (int off=128; off>0; off>>=1) {
    if (t<off) { red[0][t]+=red[0][t+off]; red[1][t]+=red[1][t+off]; }
    __syncthreads();
  }
  if (t==0) {
    const float count = (float)BC_ * 32.0f;
    float mu = red[0][0]/count;
    float var = red[1][0]/count - mu*mu;
    float sc = rsqrtf(var + EPS_) * bnw[n];
    scale[n] = sc;
    shift[n] = bnb[n] - mu*sc;
  }
}

// ---------- K3: BN2 statistics of gelu(conv(bn1(h1)) + cb) ----------
__global__ __launch_bounds__(256) void k3_bn2stats(
    const float* __restrict__ s_raw, const float* __restrict__ rowpar,
    const float* __restrict__ fc1_w, const float* __restrict__ fc1_b,
    const float* __restrict__ scale1, const float* __restrict__ shift1,
    const float* __restrict__ conv_w, const float* __restrict__ conv_b,
    float* __restrict__ partials) {
  __shared__ float sl[GR_*SROW_];
  __shared__ float w1[512];
  __shared__ float b1[32];
  __shared__ float al[GR_];
  __shared__ float sc1[64], sh1[64], cw[192], cb[64];
  __shared__ float red[2][GR_*64];
  int t = threadIdx.x;
  int row0 = blockIdx.x*GR_;
  if (t < GR_) al[t] = rowpar[(size_t)(row0+t)*4];
  for (int idx=t; idx<512; idx+=256) w1[idx] = fc1_w[idx];
  if (t < 32) b1[t] = fc1_b[t];
  if (t < 64) { sc1[t]=scale1[t]; sh1[t]=shift1[t]; cb[t]=conv_b[t]; }
  if (t >= 64 && t < 256) cw[t-64] = conv_w[t-64];
  __syncthreads();
  for (int idx=t; idx<GR_*520; idx+=256) {
    int rr = idx/520, cc = idx - rr*520;
    sl[rr*SROW_+cc] = s_raw[(size_t)(row0+rr)*SROW_+cc] * al[rr];
  }
  __syncthreads();
  int lr = t >> 4, ng = t & 15;
  for (int q=0;q<4;++q) {
    int n = ng + 16*q;
    float sp[16];
    #pragma unroll
    for (int p=0;p<16;++p) sp[p] = sl[lr*SROW_ + n*8 + p];
    float scn = sc1[n], shn = sh1[n];
    float h[32];
    #pragma unroll
    for (int hid=0; hid<32; ++hid) {
      float acc = b1[hid];
      #pragma unroll
      for (int p=0;p<16;++p) acc = fmaf(sp[p], w1[hid*16+p], acc);
      h[hid] = fmaf(gelu_f(acc), scn, shn);
    }
    float w0=cw[n*3], wm=cw[n*3+1], wpp=cw[n*3+2], cbn=cb[n];
    float s1=0.f, s2=0.f;
    #pragma unroll
    for (int k2=0;k2<32;++k2) {
      float cv = cbn;
      if (k2>0)  cv = fmaf(h[k2-1], w0, cv);
      cv = fmaf(h[k2], wm, cv);
      if (k2<31) cv = fmaf(h[k2+1], wpp, cv);
      float gv = gelu_f(cv);
      s1 += gv; s2 = fmaf(gv,gv,s2);
    }
    red[0][lr*64+n]=s1; red[1][lr*64+n]=s2;
  }
  __syncthreads();
  if (t < 64) {
    float S1=0.f, S2=0.f;
    for (int lr2=0; lr2<GR_; ++lr2) { S1 += red[0][lr2*64+t]; S2 += red[1][lr2*64+t]; }
    partials[((size_t)blockIdx.x*64+t)*2+0] = S1;
    partials[((size_t)blockIdx.x*64+t)*2+1] = S2;
  }
}

// ---------- K5: full per-row pipeline + folded output GEMV ----------
__global__ __launch_bounds__(256) void k5_final(
    const float* __restrict__ s_raw, const float* __restrict__ t_raw,
    const float* __restrict__ rowpar,
    const float* __restrict__ fc1_w, const float* __restrict__ fc1_b,
    const float* __restrict__ scale1, const float* __restrict__ shift1,
    const float* __restrict__ conv_w, const float* __restrict__ conv_b,
    const float* __restrict__ scale2, const float* __restrict__ shift2,
    const float* __restrict__ fc2_w, const float* __restrict__ fc2_b,
    const float* __restrict__ m1_w, const float* __restrict__ m1_b,
    const float* __restrict__ m2_w, const float* __restrict__ m2_b,
    const float* __restrict__ gl_scale,
    const float* __restrict__ ln_w, const float* __restrict__ ln_b,
    const float* __restrict__ W_sfT, const float* __restrict__ W_tfT,
    const float* __restrict__ biasc,
    const float* __restrict__ rev_b,
    float* __restrict__ out) {
  __shared__ float sl[RB_*SROW_];   // scaled seasonal rows
  __shared__ float yl[RB_*1024];    // LN'd y
  __shared__ float pl[RB_*64];
  __shared__ float hl[RB_*128];
  __shared__ float wl[RB_*64];
  __shared__ float rp[RB_*4];
  __shared__ float w1[512], b1[32], cw[192], cb[64];
  __shared__ float sc1[64], sh1[64], sc2[64], sh2[64];
  __shared__ float w2s[512], b2s[16], lnw[16], lnb[16];
  int t = threadIdx.x;
  int row0 = blockIdx.x*RB_;
  if (t < RB_*4) rp[t] = rowpar[(size_t)row0*4 + t];
  for (int idx=t; idx<512; idx+=256) { w1[idx]=fc1_w[idx]; w2s[idx]=fc2_w[idx]; }
  if (t<32) b1[t]=fc1_b[t];
  if (t<16) { b2s[t]=fc2_b[t]; lnw[t]=ln_w[t]; lnb[t]=ln_b[t]; }
  if (t<64) { sc1[t]=scale1[t]; sh1[t]=shift1[t]; sc2[t]=scale2[t]; sh2[t]=shift2[t]; cb[t]=conv_b[t]; }
  if (t>=64 && t<256) cw[t-64]=conv_w[t-64];
  __syncthreads();
  for (int idx=t; idx<RB_*520; idx+=256) {
    int rr = idx/520, cc = idx - rr*520;
    sl[rr*SROW_+cc] = s_raw[(size_t)(row0+rr)*SROW_+cc] * rp[rr*4+0];
  }
  __syncthreads();
  float glv = gl_scale[0];
  // P1: pooled
  for (int idx=t; idx<RB_*64; idx+=256) {
    int rr = idx>>6, n = idx&63;
    float s=0.f;
    #pragma unroll
    for (int p=0;p<16;++p) s += sl[rr*SROW_ + n*8 + p];
    pl[idx] = s*(1.0f/16.0f);
  }
  __syncthreads();
  // P2: hidden = gelu(m1 @ pooled + b)
  for (int idx=t; idx<RB_*128; idx+=256) {
    int rr = idx>>7, i = idx&127;
    float acc = m1_b[i];
    for (int k2=0;k2<64;++k2) acc = fmaf(pl[rr*64+k2], m1_w[i*64+k2], acc);
    hl[idx] = gelu_f(acc);
  }
  __syncthreads();
  // P3: w = sigmoid(m2 @ hidden + b)
  for (int idx=t; idx<RB_*64; idx+=256) {
    int rr = idx>>6, n = idx&63;
    float acc = m2_b[n];
    for (int k2=0;k2<128;++k2) acc = fmaf(hl[rr*128+k2], m2_w[n*128+k2], acc);
    wl[idx] = 1.0f/(1.0f + expf(-acc));
  }
  __syncthreads();
  // P4: per-(row,n) pipeline -> y (LayerNorm'd) in LDS
  for (int idx=t; idx<RB_*64; idx+=256) {
    int rr = idx>>6, n = idx&63;
    float sp[16];
    #pragma unroll
    for (int p=0;p<16;++p) sp[p] = sl[rr*SROW_ + n*8 + p];
    float scn=sc1[n], shn=sh1[n];
    float h[32];
    #pragma unroll
    for (int hid=0;hid<32;++hid) {
      float acc=b1[hid];
      #pragma unroll
      for (int p=0;p<16;++p) acc=fmaf(sp[p], w1[hid*16+p], acc);
      h[hid]=fmaf(gelu_f(acc), scn, shn);
    }
    float w0=cw[n*3], wm=cw[n*3+1], wpp=cw[n*3+2], cbn=cb[n];
    float sc2n=sc2[n], sh2n=sh2[n];
    float h2[32];
    #pragma unroll
    for (int k2=0;k2<32;++k2) {
      float cv=cbn;
      if (k2>0)  cv=fmaf(h[k2-1], w0, cv);
      cv=fmaf(h[k2], wm, cv);
      if (k2<31) cv=fmaf(h[k2+1], wpp, cv);
      h2[k2]=fmaf(gelu_f(cv), sc2n, sh2n);
    }
    float smul = 3.0f + glv*wl[idx];
    float yv[16]; float mu=0.f;
    #pragma unroll
    for (int p=0;p<16;++p) {
      float acc=b2s[p];
      #pragma unroll
      for (int hid=0;hid<32;++hid) acc=fmaf(h2[hid], w2s[p*32+hid], acc);
      acc = fmaf(sp[p], smul, acc);
      yv[p]=acc; mu+=acc;
    }
    mu *= (1.0f/16.0f);
    float var=0.f;
    #pragma unroll
    for (int p=0;p<16;++p){ float d=yv[p]-mu; var=fmaf(d,d,var); }
    var *= (1.0f/16.0f);
    float rs = rsqrtf(var + EPS_);
    #pragma unroll
    for (int p=0;p<16;++p) yl[rr*1024 + n*16 + p] = fmaf((yv[p]-mu)*rs, lnw[p], lnb[p]);
  }
  __syncthreads();
  // P5: folded output GEMV + inverse RevIN + strided write
  {
    int rr = t>>5, j0 = t&31;
    int row = row0+rr;
    int b = row/C_, c = row - b*C_;
    float a_r = rp[rr*4+0], g_r = rp[rr*4+1];
    float meanv = rp[rr*4+2], inva = rp[rr*4+3];
    float rbc = rev_b[c];
    float acc0=biasc[j0], acc1=biasc[j0+32], acc2=biasc[j0+64];
    for (int k2=0;k2<1024;++k2) {
      float yv = yl[rr*1024+k2];
      const float* wr = W_sfT + (size_t)k2*96 + j0;
      acc0 = fmaf(yv, wr[0],  acc0);
      acc1 = fmaf(yv, wr[32], acc1);
      acc2 = fmaf(yv, wr[64], acc2);
    }
    const float* trp = t_raw + (size_t)row*L_;
    for (int l=0;l<512;++l) {
      float tv = fmaf(trp[l], a_r, g_r);
      const float* wr = W_tfT + (size_t)l*96 + j0;
      acc0 = fmaf(tv, wr[0],  acc0);
      acc1 = fmaf(tv, wr[32], acc1);
      acc2 = fmaf(tv, wr[64], acc2);
    }
    size_t obase = ((size_t)b*PRED_)*C_ + c;
    out[obase + (size_t)j0*C_]      = (acc0 - rbc)*inva + meanv;
    out[obase + (size_t)(j0+32)*C_] = (acc1 - rbc)*inva + meanv;
    out[obase + (size_t)(j0+64)*C_] = (acc2 - rbc)*inva + meanv;
  }
}

extern "C" void kernel_launch(void* const* d_in, const int* in_sizes, int n_in,
                              void* d_out, int out_size, void* d_ws, size_t ws_size,
                              hipStream_t stream) {
  const float* x      = (const float*)d_in[0];
  const float* rev_w  = (const float*)d_in[1];
  const float* rev_b  = (const float*)d_in[2];
  const float* fc1_w  = (const float*)d_in[3];
  const float* fc1_b  = (const float*)d_in[4];
  const float* bn1_w  = (const float*)d_in[5];
  const float* bn1_b  = (const float*)d_in[6];
  const float* conv_w = (const float*)d_in[7];
  const float* conv_b = (const float*)d_in[8];
  const float* bn2_w  = (const float*)d_in[9];
  const float* bn2_b  = (const float*)d_in[10];
  const float* fc2_w  = (const float*)d_in[11];
  const float* fc2_b  = (const float*)d_in[12];
  const float* m1_w   = (const float*)d_in[13];
  const float* m1_b   = (const float*)d_in[14];
  const float* m2_w   = (const float*)d_in[15];
  const float* m2_b   = (const float*)d_in[16];
  const float* gl     = (const float*)d_in[17];
  const float* ln_w   = (const float*)d_in[18];
  const float* ln_b   = (const float*)d_in[19];
  const float* seas_w = (const float*)d_in[20];
  const float* seas_b = (const float*)d_in[21];
  const float* tr_w   = (const float*)d_in[22];
  const float* tr_b   = (const float*)d_in[23];
  const float* fus_w  = (const float*)d_in[24];
  const float* fus_b  = (const float*)d_in[25];
  float* out = (float*)d_out;
  float* ws = (float*)d_ws;

  float* W_sfT   = ws;                 // 98304
  float* W_tfT   = ws + 98304;         // 49152
  float* biasc   = ws + 147456;        // 128 (96 used)
  float* scale1  = ws + 147584;        // 64
  float* shift1  = ws + 147648;        // 64
  float* scale2  = ws + 147712;        // 64
  float* shift2  = ws + 147776;        // 64
  float* partials= ws + 147840;        // NBLK2_*64*2 = 164352
  float* rowpar  = ws + 312192;        // BC_*4 = 82176
  float* s_raw   = ws + 394368;        // BC_*SROW_ = 10847232
  float* t_raw   = ws + 11241600;      // BC_*L_   = 10518528  (end 21760128 floats = 87 MB)

  hipLaunchKernelGGL(k0_fold,  dim3(576),  dim3(256), 0, stream, seas_w, tr_w, fus_w, W_sfT, W_tfT);
  hipLaunchKernelGGL(k0b_bias, dim3(1),    dim3(128), 0, stream, seas_b, tr_b, fus_w, fus_b, biasc);
  hipLaunchKernelGGL(k1_revin_ema, dim3(BC_/64), dim3(64), 0, stream, x, rev_w, rev_b, s_raw, t_raw, rowpar);
  hipLaunchKernelGGL(k2_bn1stats, dim3(NBLK2_), dim3(256), 0, stream, s_raw, rowpar, fc1_w, fc1_b, partials);
  hipLaunchKernelGGL(k_bnreduce, dim3(64), dim3(256), 0, stream, partials, NBLK2_, bn1_w, bn1_b, scale1, shift1);
  hipLaunchKernelGGL(k3_bn2stats, dim3(NBLK2_), dim3(256), 0, stream, s_raw, rowpar, fc1_w, fc1_b, scale1, shift1, conv_w, conv_b, partials);
  hipLaunchKernelGGL(k_bnreduce, dim3(64), dim3(256), 0, stream, partials, NBLK2_, bn2_w, bn2_b, scale2, shift2);
  hipLaunchKernelGGL(k5_final, dim3(BC_/RB_), dim3(256), 0, stream,
    s_raw, t_raw, rowpar, fc1_w, fc1_b, scale1, shift1, conv_w, conv_b,
    scale2, shift2, fc2_w, fc2_b, m1_w, m1_b, m2_w, m2_b, gl, ln_w, ln_b,
    W_sfT, W_tfT, biasc, rev_b, out);
}